// Round 1
// baseline (351.036 us; speedup 1.0000x reference)
//
#include <hip/hip_runtime.h>

typedef _Float16 f16;
typedef _Float16 f16x8 __attribute__((ext_vector_type(8)));
typedef _Float16 f16x4 __attribute__((ext_vector_type(4)));
typedef float f32x4 __attribute__((ext_vector_type(4)));

// async global->LDS, 16B per lane. LDS dest must be linear: base + lane*16.
#define GLL(gp, lp) __builtin_amdgcn_global_load_lds( \
    (const __attribute__((address_space(1))) void*)(gp), \
    (__attribute__((address_space(3))) void*)(lp), 16, 0, 0)

// ---------------------------------------------------------------------------
// prep_w: fp16 hi/lo split of weights + exact fp32 ||w||^2. One wave/neuron.
// ---------------------------------------------------------------------------
__global__ void prep_w_kernel(const float* __restrict__ w, f16* __restrict__ whi,
                              f16* __restrict__ wlo, float* __restrict__ wnorm) {
    int wv = blockIdx.x * 4 + (threadIdx.x >> 6);
    int lane = threadIdx.x & 63;
    float4 v = reinterpret_cast<const float4*>(w + (size_t)wv * 256)[lane];
    float vv[4] = {v.x, v.y, v.z, v.w};
    f16x4 h, l;
    float ss = 0.f;
#pragma unroll
    for (int i = 0; i < 4; i++) {
        f16 hh = (f16)vv[i];
        h[i] = hh;
        l[i] = (f16)(vv[i] - (float)hh);
        ss += vv[i] * vv[i];
    }
    *(f16x4*)(whi + (size_t)wv * 256 + lane * 4) = h;
    *(f16x4*)(wlo + (size_t)wv * 256 + lane * 4) = l;
#pragma unroll
    for (int off = 32; off > 0; off >>= 1) ss += __shfl_down(ss, off);
    if (lane == 0) wnorm[wv] = ss;
}

// ---------------------------------------------------------------------------
// prep_x: fp16 hi/lo split of x + LDS-tiled transpose xT[d][b] (hi only)
// + bmu init. Tiles 64x64.
// ---------------------------------------------------------------------------
__global__ void prep_x_kernel(const float* __restrict__ x, f16* __restrict__ xhi,
                              f16* __restrict__ xlo, f16* __restrict__ xT,
                              unsigned long long* __restrict__ bmu) {
    __shared__ f16 tile[64][72];
    const int b0 = blockIdx.x * 64;   // 64 blocks
    const int d0 = blockIdx.y * 64;   // 4 blocks
    const int t = threadIdx.x;
    if (blockIdx.y == 0 && blockIdx.x < 16) bmu[blockIdx.x * 256 + t] = ~0ull;
    const int lb = t >> 2, dq = t & 3;
    const float* src = x + (size_t)(b0 + lb) * 256 + d0 + dq * 16;
    f16x8 h[2], l[2];
#pragma unroll
    for (int q = 0; q < 4; q++) {
        float4 v = reinterpret_cast<const float4*>(src)[q];
        float vv[4] = {v.x, v.y, v.z, v.w};
#pragma unroll
        for (int i = 0; i < 4; i++) {
            int idx = q * 4 + i;
            f16 hh = (f16)vv[i];
            h[idx >> 3][idx & 7] = hh;
            l[idx >> 3][idx & 7] = (f16)(vv[i] - (float)hh);
        }
    }
    f16* dh = xhi + (size_t)(b0 + lb) * 256 + d0 + dq * 16;
    f16* dl = xlo + (size_t)(b0 + lb) * 256 + d0 + dq * 16;
    *(f16x8*)dh = h[0]; *(f16x8*)(dh + 8) = h[1];
    *(f16x8*)dl = l[0]; *(f16x8*)(dl + 8) = l[1];
#pragma unroll
    for (int i = 0; i < 16; i++) tile[lb][dq * 16 + i] = (i < 8) ? h[0][i] : h[1][i - 8];
    __syncthreads();
    const int dlc = t >> 2, bq = t & 3;
    f16x8 o[2];
#pragma unroll
    for (int i = 0; i < 16; i++) o[i >> 3][i & 7] = tile[bq * 16 + i][dlc];
    f16* dst = xT + (size_t)(d0 + dlc) * 4096 + b0 + bq * 16;
    *(f16x8*)dst = o[0]; *(f16x8*)(dst + 8) = o[1];
}

// ---------------------------------------------------------------------------
// gemm_argmin: scores = wnorm[n] - 2 * sum_k xcat[b,k]*wcat[n,k], K=768
// (fp16 hi/lo 3-term split: [xhi|xhi|xlo] . [whi|wlo|whi]).
// 128x128 tile, BK=64, 4 waves (2x2), mfma_f32_16x16x32_f16.
// Per-row argmin -> packed u64 atomicMin.
// ---------------------------------------------------------------------------
__launch_bounds__(256, 2)
__global__ void gemm_argmin_kernel(const f16* __restrict__ xhi, const f16* __restrict__ xlo,
                                   const f16* __restrict__ whi, const f16* __restrict__ wlo,
                                   const float* __restrict__ wnorm,
                                   unsigned long long* __restrict__ bmu) {
    __shared__ f16 As[128][64];
    __shared__ f16 Bs[128][64];
    __shared__ float s_wn[128];
    const int m0 = blockIdx.x * 128;   // 32
    const int n0 = blockIdx.y * 128;   // 128
    const int tid = threadIdx.x;
    const int lane = tid & 63, wid = tid >> 6;
    const int wm = wid >> 1, wn = wid & 1;
    const int l15 = lane & 15, l4 = lane >> 4;
    if (tid < 128) s_wn[tid] = wnorm[n0 + tid];
    f32x4 acc[4][4] = {};
    for (int kt = 0; kt < 768; kt += 64) {
        const f16* asrc = (kt >= 512) ? xlo : xhi;
        const f16* bsrc = (kt >= 256 && kt < 512) ? wlo : whi;
        const int kk = kt & 255;
        __syncthreads();
#pragma unroll
        for (int q = 0; q < 4; q++) {
            int off = tid * 16 + q * 4096;      // byte offset in 16KB tile
            int row = off >> 7;
            int colh = (off & 127) >> 1;        // f16 index within row
            GLL(asrc + (size_t)(m0 + row) * 256 + kk + colh, (char*)(&As[0][0]) + off);
        }
#pragma unroll
        for (int q = 0; q < 4; q++) {
            int off = tid * 16 + q * 4096;
            int row = off >> 7;
            int colh = (off & 127) >> 1;
            GLL(bsrc + (size_t)(n0 + row) * 256 + kk + colh, (char*)(&Bs[0][0]) + off);
        }
        __syncthreads();
#pragma unroll
        for (int ks = 0; ks < 2; ks++) {
            f16x8 af[4], bf[4];
#pragma unroll
            for (int i = 0; i < 4; i++)
                af[i] = *(const f16x8*)&As[wm * 64 + i * 16 + l15][ks * 32 + l4 * 8];
#pragma unroll
            for (int i = 0; i < 4; i++)
                bf[i] = *(const f16x8*)&Bs[wn * 64 + i * 16 + l15][ks * 32 + l4 * 8];
#pragma unroll
            for (int i = 0; i < 4; i++)
#pragma unroll
                for (int j = 0; j < 4; j++)
                    acc[i][j] = __builtin_amdgcn_mfma_f32_16x16x32_f16(af[i], bf[j], acc[i][j], 0, 0, 0);
        }
    }
    // epilogue: per-row argmin of (wnorm - 2*dot); C/D layout col=l&15, row=(l>>4)*4+reg
#pragma unroll
    for (int mi = 0; mi < 4; mi++) {
#pragma unroll
        for (int j = 0; j < 4; j++) {
            float best = 1e30f;
            int bidx = 0x7fffffff;
#pragma unroll
            for (int ni = 0; ni < 4; ni++) {
                int nl = wn * 64 + ni * 16 + l15;
                float v = s_wn[nl] - 2.0f * acc[mi][ni][j];
                int g = n0 + nl;
                if (v < best || (v == best && g < bidx)) { best = v; bidx = g; }
            }
#pragma unroll
            for (int off = 1; off < 16; off <<= 1) {
                float ov = __shfl_xor(best, off);
                int oi = __shfl_xor(bidx, off);
                if (ov < best || (ov == best && oi < bidx)) { best = ov; bidx = oi; }
            }
            if (l15 == 0) {
                unsigned u = __float_as_uint(best);
                u = (u & 0x80000000u) ? ~u : (u | 0x80000000u);
                unsigned long long key = ((unsigned long long)u << 32) | (unsigned)bidx;
                int m = m0 + wm * 64 + mi * 16 + l4 * 4 + j;
                atomicMin(&bmu[m], key);
            }
        }
    }
}

// ---------------------------------------------------------------------------
// tables: erT[r][b], ecT[c][b] Gaussian tables from BMU (LUT, no per-elem exp)
// + zero ns.
// ---------------------------------------------------------------------------
__global__ void tables_kernel(const unsigned long long* __restrict__ bmu,
                              f16* __restrict__ erT, f16* __restrict__ ecT,
                              float* __restrict__ ns) {
    __shared__ float gauss[128];
    const int tid = threadIdx.x;
    const int gb = blockIdx.x * 256 + tid;   // 16 blocks x 256
    if (tid < 128) gauss[tid] = expf(-(float)(tid * tid) / 18.0f);
#pragma unroll
    for (int i = 0; i < 4; i++) ns[blockIdx.x * 1024 + tid * 4 + i] = 0.0f;
    __syncthreads();
    const int n = (int)(bmu[gb] & 0xffffffffull);
    const int br = n >> 7, bc = n & 127;
    for (int p = 0; p < 128; p++) {
        int dr = p - br; if (dr < 0) dr = -dr;
        int dc = p - bc; if (dc < 0) dc = -dc;
        erT[(size_t)p * 4096 + gb] = (f16)gauss[dr];
        ecT[(size_t)p * 4096 + gb] = (f16)gauss[dc];
    }
}

// ---------------------------------------------------------------------------
// neigh_sum: ns[r,c] = sum_b erT[r][b]*ecT[c][b], fp32 atomics over 8 b-chunks.
// ---------------------------------------------------------------------------
__global__ void neigh_sum_kernel(const f16* __restrict__ erT, const f16* __restrict__ ecT,
                                 float* __restrict__ ns) {
    const int r = blockIdx.x, chunk = blockIdx.y;  // (128, 8)
    const int c = threadIdx.x;                     // 128
    const f16* erp = erT + (size_t)r * 4096 + chunk * 512;
    const f16* ecp = ecT + (size_t)c * 4096 + chunk * 512;
    float acc = 0.f;
    for (int b = 0; b < 512; b += 8) {
        f16x8 ev = *(const f16x8*)(erp + b);
        f16x8 cv = *(const f16x8*)(ecp + b);
#pragma unroll
        for (int i = 0; i < 8; i++) acc += (float)ev[i] * (float)cv[i];
    }
    atomicAdd(&ns[r * 128 + c], acc);
}

// ---------------------------------------------------------------------------
// gemm_update: num[n,d] = sum_b (erT[r][b]*ecT[c][b]) * xT[d][b], K=4096.
// 64-aligned n-block => single r per block; A-tile built on the fly in LDS.
// Epilogue fuses out = w*(1 - s*ns[n]) + s*num.
// Tile 64(M=n) x 128(N=d), BK=64, 4 waves (2x2: 32x64 each).
// ---------------------------------------------------------------------------
__launch_bounds__(256, 2)
__global__ void gemm_update_kernel(const f16* __restrict__ xT, const f16* __restrict__ erT,
                                   const f16* __restrict__ ecT, const float* __restrict__ w,
                                   const float* __restrict__ ns, float* __restrict__ out) {
    __shared__ f16 As[64][64];
    __shared__ f16 Bs[128][64];
    __shared__ float s_ns[64];
    const int n0 = blockIdx.x * 64;    // 256 blocks
    const int d0 = blockIdx.y * 128;   // 2 blocks
    const int r0 = n0 >> 7;
    const int c0 = n0 & 127;
    const int tid = threadIdx.x;
    const int lane = tid & 63, wid = tid >> 6;
    const int wm = wid >> 1, wn = wid & 1;
    const int l15 = lane & 15, l4 = lane >> 4;
    if (tid < 64) s_ns[tid] = ns[n0 + tid];
    f32x4 acc[2][4] = {};
    const int cc = tid >> 2;           // A-construct row (0..63)
    const int k0 = (tid & 3) * 16;     // A-construct k base
    const f16* erow = erT + (size_t)r0 * 4096;
    const f16* ecrow = ecT + (size_t)(c0 + cc) * 4096;
    for (int kt = 0; kt < 4096; kt += 64) {
        __syncthreads();
#pragma unroll
        for (int q = 0; q < 4; q++) {
            int off = tid * 16 + q * 4096;
            int row = off >> 7;
            int colh = (off & 127) >> 1;
            GLL(xT + (size_t)(d0 + row) * 4096 + kt + colh, (char*)(&Bs[0][0]) + off);
        }
        f16x8 e0 = *(const f16x8*)(erow + kt + k0);
        f16x8 e1 = *(const f16x8*)(erow + kt + k0 + 8);
        f16x8 g0 = *(const f16x8*)(ecrow + kt + k0);
        f16x8 g1 = *(const f16x8*)(ecrow + kt + k0 + 8);
        *(f16x8*)&As[cc][k0] = e0 * g0;
        *(f16x8*)&As[cc][k0 + 8] = e1 * g1;
        __syncthreads();
#pragma unroll
        for (int ks = 0; ks < 2; ks++) {
            f16x8 af[2], bf[4];
#pragma unroll
            for (int i = 0; i < 2; i++)
                af[i] = *(const f16x8*)&As[wm * 32 + i * 16 + l15][ks * 32 + l4 * 8];
#pragma unroll
            for (int i = 0; i < 4; i++)
                bf[i] = *(const f16x8*)&Bs[wn * 64 + i * 16 + l15][ks * 32 + l4 * 8];
#pragma unroll
            for (int i = 0; i < 2; i++)
#pragma unroll
                for (int j = 0; j < 4; j++)
                    acc[i][j] = __builtin_amdgcn_mfma_f32_16x16x32_f16(af[i], bf[j], acc[i][j], 0, 0, 0);
        }
    }
    const float s = 0.1f / 4096.0f;
#pragma unroll
    for (int mi = 0; mi < 2; mi++) {
#pragma unroll
        for (int ni = 0; ni < 4; ni++) {
#pragma unroll
            for (int j = 0; j < 4; j++) {
                int nloc = wm * 32 + mi * 16 + l4 * 4 + j;
                int dloc = wn * 64 + ni * 16 + l15;
                size_t gi = (size_t)(n0 + nloc) * 256 + d0 + dloc;
                float wv = w[gi];
                out[gi] = wv + s * (acc[mi][ni][j] - s_ns[nloc] * wv);
            }
        }
    }
}

// ---------------------------------------------------------------------------
extern "C" void kernel_launch(void* const* d_in, const int* in_sizes, int n_in,
                              void* d_out, int out_size, void* d_ws, size_t ws_size,
                              hipStream_t stream) {
    const float* x = (const float*)d_in[0];   // [4096, 256]
    const float* w = (const float*)d_in[1];   // [128, 128, 256]
    float* out = (float*)d_out;               // [128, 128, 256]
    char* ws = (char*)d_ws;

    f16* whi = (f16*)(ws + 0);                 // 8388608
    f16* wlo = (f16*)(ws + 8388608);           // 8388608
    f16* xhi = (f16*)(ws + 16777216);          // 2097152
    f16* xlo = (f16*)(ws + 18874368);          // 2097152
    f16* xT  = (f16*)(ws + 20971520);          // 2097152
    f16* erT = (f16*)(ws + 23068672);          // 1048576
    f16* ecT = (f16*)(ws + 24117248);          // 1048576
    float* wnorm = (float*)(ws + 25165824);    // 65536
    float* ns    = (float*)(ws + 25231360);    // 65536
    unsigned long long* bmu = (unsigned long long*)(ws + 25296896);  // 32768
    // total workspace use: 25329664 bytes (~24.2 MB)

    prep_w_kernel<<<4096, 256, 0, stream>>>(w, whi, wlo, wnorm);
    prep_x_kernel<<<dim3(64, 4), 256, 0, stream>>>(x, xhi, xlo, xT, bmu);
    gemm_argmin_kernel<<<dim3(32, 128), 256, 0, stream>>>(xhi, xlo, whi, wlo, wnorm, bmu);
    tables_kernel<<<16, 256, 0, stream>>>(bmu, erT, ecT, ns);
    neigh_sum_kernel<<<dim3(128, 8), 128, 0, stream>>>(erT, ecT, ns);
    gemm_update_kernel<<<dim3(256, 2), 256, 0, stream>>>(xT, erT, ecT, w, ns, out);
}

// Round 9
// 306.152 us; speedup vs baseline: 1.1466x; 1.1466x over previous
//
#include <hip/hip_runtime.h>

typedef _Float16 f16;
typedef _Float16 f16x8 __attribute__((ext_vector_type(8)));
typedef _Float16 f16x4 __attribute__((ext_vector_type(4)));
typedef float f32x4 __attribute__((ext_vector_type(4)));

// async global->LDS, 16B per lane. LDS dest must be linear: base + lane*16.
#define GLL(gp, lp) __builtin_amdgcn_global_load_lds( \
    (const __attribute__((address_space(1))) void*)(gp), \
    (__attribute__((address_space(3))) void*)(lp), 16, 0, 0)

// ---------------------------------------------------------------------------
// prep_w: fp16 hi/lo split of weights + exact fp32 ||w||^2. One wave/neuron.
// ---------------------------------------------------------------------------
__global__ void prep_w_kernel(const float* __restrict__ w, f16* __restrict__ whi,
                              f16* __restrict__ wlo, float* __restrict__ wnorm) {
    int wv = blockIdx.x * 4 + (threadIdx.x >> 6);
    int lane = threadIdx.x & 63;
    float4 v = reinterpret_cast<const float4*>(w + (size_t)wv * 256)[lane];
    float vv[4] = {v.x, v.y, v.z, v.w};
    f16x4 h, l;
    float ss = 0.f;
#pragma unroll
    for (int i = 0; i < 4; i++) {
        f16 hh = (f16)vv[i];
        h[i] = hh;
        l[i] = (f16)(vv[i] - (float)hh);
        ss += vv[i] * vv[i];
    }
    *(f16x4*)(whi + (size_t)wv * 256 + lane * 4) = h;
    *(f16x4*)(wlo + (size_t)wv * 256 + lane * 4) = l;
#pragma unroll
    for (int off = 32; off > 0; off >>= 1) ss += __shfl_down(ss, off);
    if (lane == 0) wnorm[wv] = ss;
}

// ---------------------------------------------------------------------------
// prep_x: fp16 hi/lo split of x + bmu init.
// ---------------------------------------------------------------------------
__global__ void prep_x_kernel(const float* __restrict__ x, f16* __restrict__ xhi,
                              f16* __restrict__ xlo, unsigned long long* __restrict__ bmu) {
    const int t = blockIdx.x * 256 + threadIdx.x;   // 1024 blocks -> 262144 threads
    if (blockIdx.x < 16) bmu[blockIdx.x * 256 + threadIdx.x] = ~0ull;
    float4 v = reinterpret_cast<const float4*>(x)[t];
    float vv[4] = {v.x, v.y, v.z, v.w};
    f16x4 h, l;
#pragma unroll
    for (int i = 0; i < 4; i++) {
        f16 hh = (f16)vv[i];
        h[i] = hh;
        l[i] = (f16)(vv[i] - (float)hh);
    }
    *(f16x4*)(xhi + (size_t)t * 4) = h;
    *(f16x4*)(xlo + (size_t)t * 4) = l;
}

// ---------------------------------------------------------------------------
// gemm_argmin: scores = wnorm[n] - 2 * sum_k xcat[b,k]*wcat[n,k], K=768
// (fp16 hi/lo 3-term split: [xhi|xhi|xlo] . [whi|wlo|whi]).
// 128x128 tile, BK=64, 4 waves (2x2), mfma_f32_16x16x32_f16.
// T2 XOR-swizzle: linear GLL dest + inverse-swizzled global source + swizzled
// ds_read col -> conflict-free b128 reads. 4 blocks/CU.
// Per-row argmin -> packed u64 atomicMin.
// ---------------------------------------------------------------------------
__launch_bounds__(256, 4)
__global__ void gemm_argmin_kernel(const f16* __restrict__ xhi, const f16* __restrict__ xlo,
                                   const f16* __restrict__ whi, const f16* __restrict__ wlo,
                                   const float* __restrict__ wnorm,
                                   unsigned long long* __restrict__ bmu) {
    __shared__ f16 As[128][64];
    __shared__ f16 Bs[128][64];
    __shared__ float s_wn[128];
    const int m0 = blockIdx.x * 128;   // 32
    const int n0 = blockIdx.y * 128;   // 128
    const int tid = threadIdx.x;
    const int lane = tid & 63, wid = tid >> 6;
    const int wm = wid >> 1, wn = wid & 1;
    const int l15 = lane & 15, l4 = lane >> 4;
    const int swz = (l15 & 7) << 3;    // f16-unit XOR (row&7)<<3; row&7 == l15&7
    if (tid < 128) s_wn[tid] = wnorm[n0 + tid];
    f32x4 acc[4][4] = {};
    for (int kt = 0; kt < 768; kt += 64) {
        const f16* asrc = (kt >= 512) ? xlo : xhi;
        const f16* bsrc = (kt >= 256 && kt < 512) ? wlo : whi;
        const int kk = kt & 255;
        __syncthreads();
#pragma unroll
        for (int q = 0; q < 4; q++) {
            int off = tid * 16 + q * 4096;      // byte offset in 16KB tile
            int row = off >> 7;
            int colh = ((off & 127) ^ ((row & 7) << 4)) >> 1;  // inverse-swz source
            GLL(asrc + (size_t)(m0 + row) * 256 + kk + colh, (char*)(&As[0][0]) + off);
        }
#pragma unroll
        for (int q = 0; q < 4; q++) {
            int off = tid * 16 + q * 4096;
            int row = off >> 7;
            int colh = ((off & 127) ^ ((row & 7) << 4)) >> 1;
            GLL(bsrc + (size_t)(n0 + row) * 256 + kk + colh, (char*)(&Bs[0][0]) + off);
        }
        __syncthreads();
#pragma unroll
        for (int ks = 0; ks < 2; ks++) {
            f16x8 af[4], bf[4];
#pragma unroll
            for (int i = 0; i < 4; i++)
                af[i] = *(const f16x8*)&As[wm * 64 + i * 16 + l15][(ks * 32 + l4 * 8) ^ swz];
#pragma unroll
            for (int i = 0; i < 4; i++)
                bf[i] = *(const f16x8*)&Bs[wn * 64 + i * 16 + l15][(ks * 32 + l4 * 8) ^ swz];
#pragma unroll
            for (int i = 0; i < 4; i++)
#pragma unroll
                for (int j = 0; j < 4; j++)
                    acc[i][j] = __builtin_amdgcn_mfma_f32_16x16x32_f16(af[i], bf[j], acc[i][j], 0, 0, 0);
        }
    }
    // epilogue: per-row argmin of (wnorm - 2*dot); C/D layout col=l&15, row=(l>>4)*4+reg
#pragma unroll
    for (int mi = 0; mi < 4; mi++) {
#pragma unroll
        for (int j = 0; j < 4; j++) {
            float best = 1e30f;
            int bidx = 0x7fffffff;
#pragma unroll
            for (int ni = 0; ni < 4; ni++) {
                int nl = wn * 64 + ni * 16 + l15;
                float v = s_wn[nl] - 2.0f * acc[mi][ni][j];
                int g = n0 + nl;
                if (v < best || (v == best && g < bidx)) { best = v; bidx = g; }
            }
#pragma unroll
            for (int off = 1; off < 16; off <<= 1) {
                float ov = __shfl_xor(best, off);
                int oi = __shfl_xor(bidx, off);
                if (ov < best || (ov == best && oi < bidx)) { best = ov; bidx = oi; }
            }
            if (l15 == 0) {
                unsigned u = __float_as_uint(best);
                u = (u & 0x80000000u) ? ~u : (u | 0x80000000u);
                unsigned long long key = ((unsigned long long)u << 32) | (unsigned)bidx;
                int m = m0 + wm * 64 + mi * 16 + l4 * 4 + j;
                atomicMin(&bmu[m], key);
            }
        }
    }
}

// ---------------------------------------------------------------------------
// zeroS: zero S (16 MB, overlays dead whi/wlo) + count (64 KB). Runs AFTER
// gemm_argmin in stream order (overlay requires deferred zeroing).
// ---------------------------------------------------------------------------
__global__ void zeroS_kernel(float4* __restrict__ S4, float4* __restrict__ count4) {
    const int t = blockIdx.x * 256 + threadIdx.x;   // 4096 blocks
    S4[t] = float4{0.f, 0.f, 0.f, 0.f};
    if (blockIdx.x < 16) count4[t] = float4{0.f, 0.f, 0.f, 0.f};
}

// ---------------------------------------------------------------------------
// scatter: S[n,d] += x[b,d] for n = bmu[b]; count[n] += 1. One wave/sample.
// ---------------------------------------------------------------------------
__global__ void scatter_kernel(const float* __restrict__ x,
                               const unsigned long long* __restrict__ bmu,
                               float* __restrict__ S, float* __restrict__ count) {
    const int b = blockIdx.x * 4 + (threadIdx.x >> 6);  // 1024 blocks x 4 waves
    const int lane = threadIdx.x & 63;
    const int n = (int)(bmu[b] & 0xffffffffull);
    float4 v = reinterpret_cast<const float4*>(x + (size_t)b * 256)[lane];
    float* dst = S + (size_t)n * 256 + lane * 4;
    atomicAdd(dst + 0, v.x);
    atomicAdd(dst + 1, v.y);
    atomicAdd(dst + 2, v.z);
    atomicAdd(dst + 3, v.w);
    if (lane == 0) atomicAdd(count + n, 1.0f);
}

// ---------------------------------------------------------------------------
// ns_pass1: cnt_r[r][bc] = sum_br g[|r-br|] * count[br][bc]. Tiny (2 MF).
// ---------------------------------------------------------------------------
__global__ void ns_pass1_kernel(const float* __restrict__ count, float* __restrict__ cnt_r) {
    __shared__ float g[128];
    const int r = blockIdx.x;     // 128
    const int bc = threadIdx.x;   // 128
    g[bc] = expf(-(float)(bc * bc) / 18.0f);
    __syncthreads();
    float acc = 0.f;
    for (int br = 0; br < 128; br++) {
        int dd = br - r; dd = dd < 0 ? -dd : dd;
        acc += g[dd] * count[br * 128 + bc];
    }
    cnt_r[r * 128 + bc] = acc;
}

// ---------------------------------------------------------------------------
// conv_r (per d-half h): T1[r][j] = sum_br g[|r-br|] * S[br][bc][h*128+dh],
// j = bc*128+dh in [0,16384). Block: j-tile of 64 in LDS [128][64] f32;
// thread owns 4 j x 8 r.
// ---------------------------------------------------------------------------
__global__ void conv_r_kernel(const float* __restrict__ S, float* __restrict__ T1, int h) {
    __shared__ float tile[128][64];
    __shared__ float g[128];
    const int tid = threadIdx.x;
    const int j0 = blockIdx.x * 64;   // 256 blocks
    if (tid < 128) g[tid] = expf(-(float)(tid * tid) / 18.0f);
    const int jbase = (j0 >> 7) * 256 + h * 128 + (j0 & 127);
#pragma unroll
    for (int q = 0; q < 8; q++) {
        int off = tid * 16 + q * 4096;
        int row = off >> 8;
        int col = (off & 255) >> 2;
        GLL(S + (size_t)row * 32768 + jbase + col, (char*)(&tile[0][0]) + off);
    }
    __syncthreads();
    const int jg = (tid & 15) * 4;
    const int r0 = (tid >> 4) * 8;
    f32x4 acc[8] = {};
    for (int br = 0; br < 128; br++) {
        f32x4 v = *(const f32x4*)&tile[br][jg];
#pragma unroll
        for (int i = 0; i < 8; i++) {
            int dd = br - (r0 + i); dd = dd < 0 ? -dd : dd;
            acc[i] += g[dd] * v;
        }
    }
#pragma unroll
    for (int i = 0; i < 8; i++)
        *(f32x4*)&T1[(size_t)(r0 + i) * 16384 + j0 + jg] = acc[i];
}

// ---------------------------------------------------------------------------
// conv_c + epilogue (per d-half h): num[c][d] = sum_bc g[|c-bc|]*T1[r][bc][d];
// ns[r][c] = sum_bc g[|c-bc|]*cnt_r[r][bc]; out = w + s*(num - ns*w). fp32.
// ---------------------------------------------------------------------------
__global__ void conv_c_kernel(const float* __restrict__ T1, const float* __restrict__ cnt_r,
                              const float* __restrict__ w, float* __restrict__ out, int h) {
    __shared__ float tile[128][64];
    __shared__ float g[128];
    __shared__ float s_cnt[128];
    __shared__ float s_ns[128];
    const int tid = threadIdx.x;
    const int r = blockIdx.x;          // 128
    const int d0 = blockIdx.y * 64;    // 2 (within the 128-wide half)
    if (tid < 128) g[tid] = expf(-(float)(tid * tid) / 18.0f);
    if (tid >= 128 && tid < 256) s_cnt[tid - 128] = cnt_r[r * 128 + (tid - 128)];
#pragma unroll
    for (int q = 0; q < 8; q++) {
        int off = tid * 16 + q * 4096;
        int row = off >> 8;            // bc
        int col = (off & 255) >> 2;    // d within tile
        GLL(T1 + (size_t)r * 16384 + (size_t)row * 128 + d0 + col, (char*)(&tile[0][0]) + off);
    }
    __syncthreads();
    if (tid < 128) {
        float acc = 0.f;
        for (int bc = 0; bc < 128; bc++) {
            int dd = tid - bc; dd = dd < 0 ? -dd : dd;
            acc += g[dd] * s_cnt[bc];
        }
        s_ns[tid] = acc;
    }
    __syncthreads();
    const int jg = (tid & 15) * 4;
    const int c0 = (tid >> 4) * 8;
    f32x4 acc[8] = {};
    for (int bc = 0; bc < 128; bc++) {
        f32x4 v = *(const f32x4*)&tile[bc][jg];
#pragma unroll
        for (int i = 0; i < 8; i++) {
            int dd = bc - (c0 + i); dd = dd < 0 ? -dd : dd;
            acc[i] += g[dd] * v;
        }
    }
    const float s = 0.1f / 4096.0f;
#pragma unroll
    for (int i = 0; i < 8; i++) {
        size_t gi = ((size_t)(r * 128 + c0 + i)) * 256 + h * 128 + d0 + jg;
        f32x4 wv = *(const f32x4*)&w[gi];
        f32x4 o = wv + s * (acc[i] - s_ns[c0 + i] * wv);
        *(f32x4*)&out[gi] = o;
    }
}

// ---------------------------------------------------------------------------
extern "C" void kernel_launch(void* const* d_in, const int* in_sizes, int n_in,
                              void* d_out, int out_size, void* d_ws, size_t ws_size,
                              hipStream_t stream) {
    const float* x = (const float*)d_in[0];   // [4096, 256]
    const float* w = (const float*)d_in[1];   // [128, 128, 256]
    float* out = (float*)d_out;               // [128, 128, 256]
    char* ws = (char*)d_ws;

    // Overlaid layout; peak use 25329664 B (== R1's proven-safe footprint).
    f16* whi = (f16*)(ws + 0);                // 8 MB  } dead after gemm_argmin
    f16* wlo = (f16*)(ws + 8388608);          // 8 MB  }
    float* S = (float*)(ws + 0);              // 16 MB  overlay (zeroed post-argmin)
    f16* xhi = (f16*)(ws + 16777216);         // 2 MB  } dead after gemm_argmin
    f16* xlo = (f16*)(ws + 18874368);         // 2 MB  }
    float* wnorm = (float*)(ws + 20971520);   // 64 KB }
    float* T1 = (float*)(ws + 16777216);      // 8 MB  overlay (d-half, conv_r->conv_c)
    unsigned long long* bmu = (unsigned long long*)(ws + 25165824);  // 32 KB
    float* count = (float*)(ws + 25198592);   // 64 KB
    float* cnt_r = (float*)(ws + 25264128);   // 64 KB
    // end: 25329664

    prep_w_kernel<<<4096, 256, 0, stream>>>(w, whi, wlo, wnorm);
    prep_x_kernel<<<1024, 256, 0, stream>>>(x, xhi, xlo, bmu);
    gemm_argmin_kernel<<<dim3(32, 128), 256, 0, stream>>>(xhi, xlo, whi, wlo, wnorm, bmu);
    zeroS_kernel<<<4096, 256, 0, stream>>>((float4*)S, (float4*)count);
    scatter_kernel<<<1024, 256, 0, stream>>>(x, bmu, S, count);
    ns_pass1_kernel<<<128, 128, 0, stream>>>(count, cnt_r);
    conv_r_kernel<<<256, 256, 0, stream>>>(S, T1, 0);
    conv_c_kernel<<<dim3(128, 2), 256, 0, stream>>>(T1, cnt_r, w, out, 0);
    conv_r_kernel<<<256, 256, 0, stream>>>(S, T1, 1);
    conv_c_kernel<<<dim3(128, 2), 256, 0, stream>>>(T1, cnt_r, w, out, 1);
}

// Round 12
// 283.193 us; speedup vs baseline: 1.2396x; 1.0811x over previous
//
#include <hip/hip_runtime.h>

typedef _Float16 f16;
typedef _Float16 f16x8 __attribute__((ext_vector_type(8)));
typedef _Float16 f16x4 __attribute__((ext_vector_type(4)));
typedef float f32x4 __attribute__((ext_vector_type(4)));

// async global->LDS, 16B per lane. LDS dest must be linear: base + lane*16.
#define GLL(gp, lp) __builtin_amdgcn_global_load_lds( \
    (const __attribute__((address_space(1))) void*)(gp), \
    (__attribute__((address_space(3))) void*)(lp), 16, 0, 0)

// ---------------------------------------------------------------------------
// prep (fused): blocks [0,4096): fp16 hi/lo split of w + fp32 ||w||^2.
// blocks [4096,5120): fp16 hi/lo split of x; first 16 also init bmu,
// next 16 zero count. Saves 1 launch vs separate prep_w/prep_x.
// ---------------------------------------------------------------------------
__global__ void prep_kernel(const float* __restrict__ w, const float* __restrict__ x,
                            f16* __restrict__ whi, f16* __restrict__ wlo,
                            float* __restrict__ wnorm, f16* __restrict__ xhi,
                            f16* __restrict__ xlo, unsigned long long* __restrict__ bmu,
                            float4* __restrict__ count4) {
    const int bid = blockIdx.x;
    const int tid = threadIdx.x;
    if (bid < 4096) {
        // ---- w path: one wave per neuron ----
        int wv = bid * 4 + (tid >> 6);
        int lane = tid & 63;
        float4 v = reinterpret_cast<const float4*>(w + (size_t)wv * 256)[lane];
        float vv[4] = {v.x, v.y, v.z, v.w};
        f16x4 h, l;
        float ss = 0.f;
#pragma unroll
        for (int i = 0; i < 4; i++) {
            f16 hh = (f16)vv[i];
            h[i] = hh;
            l[i] = (f16)(vv[i] - (float)hh);
            ss += vv[i] * vv[i];
        }
        *(f16x4*)(whi + (size_t)wv * 256 + lane * 4) = h;
        *(f16x4*)(wlo + (size_t)wv * 256 + lane * 4) = l;
#pragma unroll
        for (int off = 32; off > 0; off >>= 1) ss += __shfl_down(ss, off);
        if (lane == 0) wnorm[wv] = ss;
    } else {
        // ---- x path ----
        const int xb = bid - 4096;                  // [0,1024)
        if (xb < 16) bmu[xb * 256 + tid] = ~0ull;
        else if (xb < 32) count4[(xb - 16) * 256 + tid] = float4{0.f, 0.f, 0.f, 0.f};
        const int t = xb * 256 + tid;
        float4 v = reinterpret_cast<const float4*>(x)[t];
        float vv[4] = {v.x, v.y, v.z, v.w};
        f16x4 h, l;
#pragma unroll
        for (int i = 0; i < 4; i++) {
            f16 hh = (f16)vv[i];
            h[i] = hh;
            l[i] = (f16)(vv[i] - (float)hh);
        }
        *(f16x4*)(xhi + (size_t)t * 4) = h;
        *(f16x4*)(xlo + (size_t)t * 4) = l;
    }
}

// ---------------------------------------------------------------------------
// gemm_argmin: scores = wnorm[n] - 2 * sum_k xcat[b,k]*wcat[n,k], K=768
// (fp16 hi/lo 3-term split: [xhi|xhi|xlo] . [whi|wlo|whi]).
// 128x128 tile, BK=64, 4 waves (2x2), mfma_f32_16x16x32_f16.
// T2 XOR-swizzle: linear GLL dest + inverse-swizzled global source + swizzled
// ds_read col -> conflict-free b128 reads (R9: SQ_LDS_BANK_CONFLICT == 0).
// UNCHANGED from R9 (byte-identical) for clean attribution.
// ---------------------------------------------------------------------------
__launch_bounds__(256, 4)
__global__ void gemm_argmin_kernel(const f16* __restrict__ xhi, const f16* __restrict__ xlo,
                                   const f16* __restrict__ whi, const f16* __restrict__ wlo,
                                   const float* __restrict__ wnorm,
                                   unsigned long long* __restrict__ bmu) {
    __shared__ f16 As[128][64];
    __shared__ f16 Bs[128][64];
    __shared__ float s_wn[128];
    const int m0 = blockIdx.x * 128;   // 32
    const int n0 = blockIdx.y * 128;   // 128
    const int tid = threadIdx.x;
    const int lane = tid & 63, wid = tid >> 6;
    const int wm = wid >> 1, wn = wid & 1;
    const int l15 = lane & 15, l4 = lane >> 4;
    const int swz = (l15 & 7) << 3;    // f16-unit XOR (row&7)<<3; row&7 == l15&7
    if (tid < 128) s_wn[tid] = wnorm[n0 + tid];
    f32x4 acc[4][4] = {};
    for (int kt = 0; kt < 768; kt += 64) {
        const f16* asrc = (kt >= 512) ? xlo : xhi;
        const f16* bsrc = (kt >= 256 && kt < 512) ? wlo : whi;
        const int kk = kt & 255;
        __syncthreads();
#pragma unroll
        for (int q = 0; q < 4; q++) {
            int off = tid * 16 + q * 4096;      // byte offset in 16KB tile
            int row = off >> 7;
            int colh = ((off & 127) ^ ((row & 7) << 4)) >> 1;  // inverse-swz source
            GLL(asrc + (size_t)(m0 + row) * 256 + kk + colh, (char*)(&As[0][0]) + off);
        }
#pragma unroll
        for (int q = 0; q < 4; q++) {
            int off = tid * 16 + q * 4096;
            int row = off >> 7;
            int colh = ((off & 127) ^ ((row & 7) << 4)) >> 1;
            GLL(bsrc + (size_t)(n0 + row) * 256 + kk + colh, (char*)(&Bs[0][0]) + off);
        }
        __syncthreads();
#pragma unroll
        for (int ks = 0; ks < 2; ks++) {
            f16x8 af[4], bf[4];
#pragma unroll
            for (int i = 0; i < 4; i++)
                af[i] = *(const f16x8*)&As[wm * 64 + i * 16 + l15][(ks * 32 + l4 * 8) ^ swz];
#pragma unroll
            for (int i = 0; i < 4; i++)
                bf[i] = *(const f16x8*)&Bs[wn * 64 + i * 16 + l15][(ks * 32 + l4 * 8) ^ swz];
#pragma unroll
            for (int i = 0; i < 4; i++)
#pragma unroll
                for (int j = 0; j < 4; j++)
                    acc[i][j] = __builtin_amdgcn_mfma_f32_16x16x32_f16(af[i], bf[j], acc[i][j], 0, 0, 0);
        }
    }
    // epilogue: per-row argmin of (wnorm - 2*dot); C/D layout col=l&15, row=(l>>4)*4+reg
#pragma unroll
    for (int mi = 0; mi < 4; mi++) {
#pragma unroll
        for (int j = 0; j < 4; j++) {
            float best = 1e30f;
            int bidx = 0x7fffffff;
#pragma unroll
            for (int ni = 0; ni < 4; ni++) {
                int nl = wn * 64 + ni * 16 + l15;
                float v = s_wn[nl] - 2.0f * acc[mi][ni][j];
                int g = n0 + nl;
                if (v < best || (v == best && g < bidx)) { best = v; bidx = g; }
            }
#pragma unroll
            for (int off = 1; off < 16; off <<= 1) {
                float ov = __shfl_xor(best, off);
                int oi = __shfl_xor(bidx, off);
                if (ov < best || (ov == best && oi < bidx)) { best = ov; bidx = oi; }
            }
            if (l15 == 0) {
                unsigned u = __float_as_uint(best);
                u = (u & 0x80000000u) ? ~u : (u | 0x80000000u);
                unsigned long long key = ((unsigned long long)u << 32) | (unsigned)bidx;
                int m = m0 + wm * 64 + mi * 16 + l4 * 4 + j;
                atomicMin(&bmu[m], key);
            }
        }
    }
}

// ---------------------------------------------------------------------------
// zeroS: zero S (16 MB, overlays dead whi/wlo). Runs AFTER gemm_argmin in
// stream order (overlay requires deferred zeroing). count zeroed in prep.
// ---------------------------------------------------------------------------
__global__ void zeroS_kernel(float4* __restrict__ S4) {
    const int t = blockIdx.x * 256 + threadIdx.x;   // 4096 blocks
    S4[t] = float4{0.f, 0.f, 0.f, 0.f};
}

// ---------------------------------------------------------------------------
// scatter: S[n,d] += x[b,d] for n = bmu[b]; count[n] += 1. One wave/sample.
// ---------------------------------------------------------------------------
__global__ void scatter_kernel(const float* __restrict__ x,
                               const unsigned long long* __restrict__ bmu,
                               float* __restrict__ S, float* __restrict__ count) {
    const int b = blockIdx.x * 4 + (threadIdx.x >> 6);  // 1024 blocks x 4 waves
    const int lane = threadIdx.x & 63;
    const int n = (int)(bmu[b] & 0xffffffffull);
    float4 v = reinterpret_cast<const float4*>(x + (size_t)b * 256)[lane];
    float* dst = S + (size_t)n * 256 + lane * 4;
    atomicAdd(dst + 0, v.x);
    atomicAdd(dst + 1, v.y);
    atomicAdd(dst + 2, v.z);
    atomicAdd(dst + 3, v.w);
    if (lane == 0) atomicAdd(count + n, 1.0f);
}

// ---------------------------------------------------------------------------
// ns_pass1: cnt_r[r][bc] = sum_br g[|r-br|] * count[br][bc]. Tiny (2 MF).
// ---------------------------------------------------------------------------
__global__ void ns_pass1_kernel(const float* __restrict__ count, float* __restrict__ cnt_r) {
    __shared__ float g[128];
    const int r = blockIdx.x;     // 128
    const int bc = threadIdx.x;   // 128
    g[bc] = expf(-(float)(bc * bc) / 18.0f);
    __syncthreads();
    float acc = 0.f;
    for (int br = 0; br < 128; br++) {
        int dd = br - r; dd = dd < 0 ? -dd : dd;
        acc += g[dd] * count[br * 128 + bc];
    }
    cnt_r[r * 128 + bc] = acc;
}

// ---------------------------------------------------------------------------
// conv_r (full d, f16 output): T1[r][j] = sum_br g[|r-br|] * S[br][j],
// j = bc*256+d in [0,32768). Block: j-tile of 64 staged [128][64] f32 in LDS;
// thread owns 4 j x 8 r. T1 f16 (err into out ~1e-6) -> full-d fits 8 MB slot,
// single launch instead of two halves.
// ---------------------------------------------------------------------------
__global__ void conv_r_kernel(const float* __restrict__ S, f16* __restrict__ T1) {
    __shared__ float tile[128][64];
    __shared__ float g[128];
    const int tid = threadIdx.x;
    const int j0 = blockIdx.x * 64;   // 512 blocks
    if (tid < 128) g[tid] = expf(-(float)(tid * tid) / 18.0f);
#pragma unroll
    for (int q = 0; q < 8; q++) {
        int off = tid * 16 + q * 4096;
        int row = off >> 8;
        int col = (off & 255) >> 2;
        GLL(S + (size_t)row * 32768 + j0 + col, (char*)(&tile[0][0]) + off);
    }
    __syncthreads();
    const int jg = (tid & 15) * 4;
    const int r0 = (tid >> 4) * 8;
    f32x4 acc[8] = {};
    for (int br = 0; br < 128; br++) {
        f32x4 v = *(const f32x4*)&tile[br][jg];
#pragma unroll
        for (int i = 0; i < 8; i++) {
            int dd = br - (r0 + i); dd = dd < 0 ? -dd : dd;
            acc[i] += g[dd] * v;
        }
    }
#pragma unroll
    for (int i = 0; i < 8; i++) {
        f16x4 hv;
#pragma unroll
        for (int k = 0; k < 4; k++) hv[k] = (f16)acc[i][k];
        *(f16x4*)&T1[(size_t)(r0 + i) * 32768 + j0 + jg] = hv;
    }
}

// ---------------------------------------------------------------------------
// conv_c + epilogue (full d via grid.y=4): num[c][d] = sum_bc g[|c-bc|]*T1[r][bc][d];
// ns[r][c] = sum_bc g[|c-bc|]*cnt_r[r][bc]; out = w + s*(num - ns*w).
// ---------------------------------------------------------------------------
__global__ void conv_c_kernel(const f16* __restrict__ T1, const float* __restrict__ cnt_r,
                              const float* __restrict__ w, float* __restrict__ out) {
    __shared__ f16 tile[128][64];
    __shared__ float g[128];
    __shared__ float s_cnt[128];
    __shared__ float s_ns[128];
    const int tid = threadIdx.x;
    const int r = blockIdx.x;          // 128
    const int d0 = blockIdx.y * 64;    // 4
    if (tid < 128) g[tid] = expf(-(float)(tid * tid) / 18.0f);
    if (tid >= 128 && tid < 256) s_cnt[tid - 128] = cnt_r[r * 128 + (tid - 128)];
#pragma unroll
    for (int q = 0; q < 4; q++) {
        int off = tid * 16 + q * 4096;   // 16 KB f16 tile
        int row = off >> 7;              // bc (128 B per row)
        int colh = (off & 127) >> 1;     // f16 index within row
        GLL(T1 + (size_t)r * 32768 + (size_t)row * 256 + d0 + colh, (char*)(&tile[0][0]) + off);
    }
    __syncthreads();
    if (tid < 128) {
        float acc = 0.f;
        for (int bc = 0; bc < 128; bc++) {
            int dd = tid - bc; dd = dd < 0 ? -dd : dd;
            acc += g[dd] * s_cnt[bc];
        }
        s_ns[tid] = acc;
    }
    __syncthreads();
    const int jg = (tid & 15) * 4;
    const int c0 = (tid >> 4) * 8;
    f32x4 acc[8] = {};
    for (int bc = 0; bc < 128; bc++) {
        f16x4 hv = *(const f16x4*)&tile[bc][jg];
        f32x4 v = {(float)hv[0], (float)hv[1], (float)hv[2], (float)hv[3]};
#pragma unroll
        for (int i = 0; i < 8; i++) {
            int dd = bc - (c0 + i); dd = dd < 0 ? -dd : dd;
            acc[i] += g[dd] * v;
        }
    }
    const float s = 0.1f / 4096.0f;
#pragma unroll
    for (int i = 0; i < 8; i++) {
        size_t gi = ((size_t)(r * 128 + c0 + i)) * 256 + d0 + jg;
        f32x4 wv = *(const f32x4*)&w[gi];
        f32x4 o = wv + s * (acc[i] - s_ns[c0 + i] * wv);
        *(f32x4*)&out[gi] = o;
    }
}

// ---------------------------------------------------------------------------
extern "C" void kernel_launch(void* const* d_in, const int* in_sizes, int n_in,
                              void* d_out, int out_size, void* d_ws, size_t ws_size,
                              hipStream_t stream) {
    const float* x = (const float*)d_in[0];   // [4096, 256]
    const float* w = (const float*)d_in[1];   // [128, 128, 256]
    float* out = (float*)d_out;               // [128, 128, 256]
    char* ws = (char*)d_ws;

    // Overlaid layout; peak use 25329664 B (== R1/R9's proven-safe footprint).
    f16* whi = (f16*)(ws + 0);                // 8 MB  } dead after gemm_argmin
    f16* wlo = (f16*)(ws + 8388608);          // 8 MB  }
    float* S = (float*)(ws + 0);              // 16 MB  overlay (zeroed post-argmin)
    f16* xhi = (f16*)(ws + 16777216);         // 2 MB  } dead after gemm_argmin
    f16* xlo = (f16*)(ws + 18874368);         // 2 MB  }
    float* wnorm = (float*)(ws + 20971520);   // 64 KB }
    f16* T1 = (f16*)(ws + 16777216);          // 8 MB f16 [128][32768] overlay
    unsigned long long* bmu = (unsigned long long*)(ws + 25165824);  // 32 KB
    float* count = (float*)(ws + 25198592);   // 64 KB (zeroed in prep)
    float* cnt_r = (float*)(ws + 25264128);   // 64 KB
    // end: 25329664

    prep_kernel<<<5120, 256, 0, stream>>>(w, x, whi, wlo, wnorm, xhi, xlo, bmu,
                                          (float4*)count);
    gemm_argmin_kernel<<<dim3(32, 128), 256, 0, stream>>>(xhi, xlo, whi, wlo, wnorm, bmu);
    zeroS_kernel<<<4096, 256, 0, stream>>>((float4*)S);
    scatter_kernel<<<1024, 256, 0, stream>>>(x, bmu, S, count);
    ns_pass1_kernel<<<128, 128, 0, stream>>>(count, cnt_r);
    conv_r_kernel<<<512, 256, 0, stream>>>(S, T1);
    conv_c_kernel<<<dim3(128, 4), 256, 0, stream>>>(T1, cnt_r, w, out);
}